// Round 2
// baseline (272.110 us; speedup 1.0000x reference)
//
#include <hip/hip_runtime.h>
#include <cstdint>
#include <cstddef>

typedef float f32x4 __attribute__((ext_vector_type(4)));
typedef short s16x8 __attribute__((ext_vector_type(8)));
typedef short s16x4 __attribute__((ext_vector_type(4)));

#define MFMA_BF16(a, b, c) __builtin_amdgcn_mfma_f32_16x16x32_bf16((a), (b), (c), 0, 0, 0)

// async global->LDS DMA, 16B/lane: lands at ldsbase + lane*16 (wave-uniform base)
#define GLD16(g, l)                                                            \
  __builtin_amdgcn_global_load_lds(                                            \
      (const __attribute__((address_space(1))) void*)(g),                      \
      (__attribute__((address_space(3))) void*)(l), 16, 0, 0)

__device__ __forceinline__ unsigned short f2bf(float f) {
  unsigned int u = __float_as_uint(f);
  u += 0x7FFFu + ((u >> 16) & 1u);
  return (unsigned short)(u >> 16);
}

__device__ __forceinline__ s16x8 cvt8(const float* __restrict__ src) {
  const float4 f0 = *(const float4*)src;
  const float4 f1 = *(const float4*)(src + 4);
  s16x8 h;
  h[0] = (short)f2bf(f0.x); h[1] = (short)f2bf(f0.y);
  h[2] = (short)f2bf(f0.z); h[3] = (short)f2bf(f0.w);
  h[4] = (short)f2bf(f1.x); h[5] = (short)f2bf(f1.y);
  h[6] = (short)f2bf(f1.z); h[7] = (short)f2bf(f1.w);
  return h;
}

// ---------------------------------------------------------------------------
// cvt_bf16: x -> xb, w_qkv[0:1024] -> wb (V-proj rows dead: reference builds
// v2 from k), w_out -> wob. Memory-bound one-shot.
// ---------------------------------------------------------------------------
#define XN 16777216   // 4*8192*512
#define WQN 524288    // 1024*512
__global__ __launch_bounds__(256)
void cvt_bf16(const float* __restrict__ x, const float* __restrict__ wqkv,
              const float* __restrict__ wout, unsigned short* __restrict__ xb,
              unsigned short* __restrict__ wb, unsigned short* __restrict__ wob) {
  const size_t i = (size_t)(blockIdx.x * 256 + threadIdx.x) * 8;
  const float* src;
  unsigned short* dst;
  if (i < XN) { src = x + i; dst = xb + i; }
  else if (i < XN + WQN) { src = wqkv + (i - XN); dst = wb + (i - XN); }
  else { src = wout + (i - XN - WQN); dst = wob + (i - XN - WQN); }
  *(s16x8*)dst = cvt8(src);
}

// ---------------------------------------------------------------------------
// gemm_qk: [Q|K] = xb @ wb^T. M=32768 N=1024 K=512. m97 structure, GLD16 both
// operands, XOR-swizzled LDS. SWAPPED staging (W->As, x->Bs, block-uniform
// pointer select): D comes out transposed -> packed 8B Q/K stores.
// XCD-aware map: each XCD runs all 8 n-tiles of one m-tile consecutively.
// ---------------------------------------------------------------------------
__global__ __launch_bounds__(256)
void gemm_qk(const unsigned short* __restrict__ xb, const unsigned short* __restrict__ wb,
             unsigned short* __restrict__ Q, unsigned short* __restrict__ K) {
  __shared__ unsigned short As[128 * 64];  // W tile
  __shared__ unsigned short Bs[128 * 64];  // x tile
  const int t = threadIdx.x, lane = t & 63, wid = t >> 6;
  const int wm = wid >> 1, wn = wid & 1;
  const int nl = lane & 15, quad = lane >> 4;
  const int sub = lane >> 3, lblk = (lane & 7) ^ sub;
  const int l = blockIdx.x;
  const int xcd = l & 7, g = l >> 3;
  const int mt = (g >> 3) * 8 + xcd, nt = g & 7;
  const int m0 = mt * 128, n0 = nt * 128;

  const f32x4 zero = {0.f, 0.f, 0.f, 0.f};
  f32x4 acc[4][4];
#pragma unroll
  for (int i = 0; i < 4; ++i)
#pragma unroll
    for (int j = 0; j < 4; ++j) acc[i][j] = zero;

  const unsigned short* gX = xb + (size_t)(m0 + wid * 32 + sub) * 512 + lblk * 8;
  const unsigned short* gW = wb + (size_t)(n0 + wid * 32 + sub) * 512 + lblk * 8;

  for (int kc = 0; kc < 512; kc += 64) {
#pragma unroll
    for (int ii = 0; ii < 4; ++ii) {
      GLD16(gW + kc + (size_t)(ii * 8) * 512, &As[(wid * 32 + ii * 8) * 64]);
      GLD16(gX + kc + (size_t)(ii * 8) * 512, &Bs[(wid * 32 + ii * 8) * 64]);
    }
    __syncthreads();
#pragma unroll
    for (int ks = 0; ks < 2; ++ks) {
      s16x8 af[4], bf[4];
#pragma unroll
      for (int i = 0; i < 4; ++i)
        af[i] = *(const s16x8*)&As[(wm * 64 + i * 16 + nl) * 64 +
                                   (((ks * 4 + quad) ^ (nl & 7)) * 8)];
#pragma unroll
      for (int j = 0; j < 4; ++j)
        bf[j] = *(const s16x8*)&Bs[(wn * 64 + j * 16 + nl) * 64 +
                                   (((ks * 4 + quad) ^ (nl & 7)) * 8)];
#pragma unroll
      for (int i = 0; i < 4; ++i)
#pragma unroll
        for (int j = 0; j < 4; ++j) acc[i][j] = MFMA_BF16(af[i], bf[j], acc[i][j]);
    }
    __syncthreads();
  }
  // D rows = W-feature n (contiguous in reg r), cols = seq m -> packed stores
#pragma unroll
  for (int i = 0; i < 4; ++i) {
    const int n = n0 + wm * 64 + i * 16 + quad * 4;
    unsigned short* base = (n < 512 ? Q : K);
    const int nn = n & 511;
#pragma unroll
    for (int j = 0; j < 4; ++j) {
      const int m = m0 + wn * 64 + j * 16 + nl;
      s16x4 h;
#pragma unroll
      for (int r = 0; r < 4; ++r) h[r] = (short)f2bf(acc[i][j][r]);
      *(s16x4*)&base[(size_t)m * 512 + nn] = h;
    }
  }
}

// ---------------------------------------------------------------------------
// gemm_kwt: KWT[b][o][seq] = (K @ wob^T)^T — output projection hoisted before
// attention (out@w_out^T == P@(K2@w_out^T)). Normal operand order: D rows =
// seq (contiguous in r) -> packed 8B transposed stores. XCD-swizzled.
// ---------------------------------------------------------------------------
__global__ __launch_bounds__(256)
void gemm_kwt(const unsigned short* __restrict__ K, const unsigned short* __restrict__ wob,
              unsigned short* __restrict__ KWT) {
  __shared__ unsigned short As[128 * 64];
  __shared__ unsigned short Bs[128 * 64];
  const int t = threadIdx.x, lane = t & 63, wid = t >> 6;
  const int wm = wid >> 1, wn = wid & 1;
  const int nl = lane & 15, quad = lane >> 4;
  const int sub = lane >> 3, lblk = (lane & 7) ^ sub;
  const int l = blockIdx.x;
  const int xcd = l & 7, g = l >> 3;
  const int mt = (g >> 2) * 8 + xcd, nt = g & 3;
  const int m0 = mt * 128, n0 = nt * 128;

  const f32x4 zero = {0.f, 0.f, 0.f, 0.f};
  f32x4 acc[4][4];
#pragma unroll
  for (int i = 0; i < 4; ++i)
#pragma unroll
    for (int j = 0; j < 4; ++j) acc[i][j] = zero;

  const unsigned short* gA = K + (size_t)(m0 + wid * 32 + sub) * 512 + lblk * 8;
  const unsigned short* gB = wob + (size_t)(n0 + wid * 32 + sub) * 512 + lblk * 8;

  for (int kc = 0; kc < 512; kc += 64) {
#pragma unroll
    for (int ii = 0; ii < 4; ++ii) {
      GLD16(gA + kc + (size_t)(ii * 8) * 512, &As[(wid * 32 + ii * 8) * 64]);
      GLD16(gB + kc + (size_t)(ii * 8) * 512, &Bs[(wid * 32 + ii * 8) * 64]);
    }
    __syncthreads();
#pragma unroll
    for (int ks = 0; ks < 2; ++ks) {
      s16x8 af[4], bf[4];
#pragma unroll
      for (int i = 0; i < 4; ++i)
        af[i] = *(const s16x8*)&As[(wm * 64 + i * 16 + nl) * 64 +
                                   (((ks * 4 + quad) ^ (nl & 7)) * 8)];
#pragma unroll
      for (int j = 0; j < 4; ++j)
        bf[j] = *(const s16x8*)&Bs[(wn * 64 + j * 16 + nl) * 64 +
                                   (((ks * 4 + quad) ^ (nl & 7)) * 8)];
#pragma unroll
      for (int i = 0; i < 4; ++i)
#pragma unroll
        for (int j = 0; j < 4; ++j) acc[i][j] = MFMA_BF16(af[i], bf[j], acc[i][j]);
    }
    __syncthreads();
  }
#pragma unroll
  for (int i = 0; i < 4; ++i) {
    const int ms = m0 + wm * 64 + i * 16 + quad * 4;
    const int b = ms >> 13, ns = ms & 8191;
#pragma unroll
    for (int j = 0; j < 4; ++j) {
      const int o = n0 + wn * 64 + j * 16 + nl;
      s16x4 h;
#pragma unroll
      for (int r = 0; r < 4; ++r) h[r] = (short)f2bf(acc[i][j][r]);
      *(s16x4*)&KWT[(size_t)(b * 512 + o) * 8192 + ns] = h;
    }
  }
}

// ---------------------------------------------------------------------------
// attn32 (attn64 v3): one block = 32 Q-rows of one window (4 blocks/window,
// grid 1024 -> 4 blocks/CU, 16 waves/CU: round-1 showed the kernel is
// wave-starved, not barrier-bound — grid 512 capped it at 8 waves/CU).
// Operands still direct-from-L2 (no staging); only P relayouts through LDS.
// __launch_bounds__(256,4) pins VGPR <=128 so 4 waves/SIMD are schedulable.
// Quad-XCD swizzle: all 4 quarter-blocks of a window share one XCD's L2
// (bx = gg*32 + qtr*8 + xcd, window = gg*8 + xcd).
// ---------------------------------------------------------------------------
__global__ __launch_bounds__(256, 4)
void attn64(const unsigned short* __restrict__ Q, const unsigned short* __restrict__ K,
            const unsigned short* __restrict__ KWT, const float* __restrict__ bias,
            float* __restrict__ out) {
  __shared__ unsigned short Ps[32 * 256];  // 16KB: P, swizzled row-major
  __shared__ float redm[128];
  __shared__ float reds[128];
  const int t = threadIdx.x, lane = t & 63, wid = t >> 6;
  const int wn = wid;  // 4 waves split the 256 sim cols
  const int nl = lane & 15, quad = lane >> 4;
  // quad-XCD decode: bx = gg*32 + qtr*8 + xcd
  const int bx = blockIdx.x;
  const int xcd = bx & 7, qtr = (bx >> 3) & 3, gg = bx >> 5;
  const int wb = gg * 8 + xcd, b = wb >> 6, w = wb & 63;

  const f32x4 zero = {0.f, 0.f, 0.f, 0.f};
  f32x4 acc[2][4];
#pragma unroll
  for (int i = 0; i < 2; ++i)
#pragma unroll
    for (int j = 0; j < 4; ++j) acc[i][j] = zero;

  const unsigned short* Qb = Q + (size_t)(b * 8192 + w * 128 + qtr * 32) * 512;
  const unsigned short* Kb = K + (size_t)(b * 8192) * 512;

  // per-lane fragment row pointers (constant over the K loop)
  const unsigned short* qptr[2];
  const unsigned short* kptr[4];
#pragma unroll
  for (int i = 0; i < 2; ++i) qptr[i] = Qb + (size_t)(i * 16 + nl) * 512;
#pragma unroll
  for (int j = 0; j < 4; ++j) {
    int seq = w * 128 - 128 + wn * 64 + j * 16 + nl;
    if (seq < 0) seq = 0;  // window 0: finite garbage, neutralized pre-softmax
    kptr[j] = Kb + (size_t)seq * 512;
  }

  // phase 1: sim = Q . K2^T, fragments direct from L2, no barriers
#pragma unroll 4
  for (int kc = 0; kc < 512; kc += 64) {
#pragma unroll
    for (int ks = 0; ks < 2; ++ks) {
      const int off = kc + (ks * 4 + quad) * 8;
      s16x8 af[2], bf[4];
#pragma unroll
      for (int i = 0; i < 2; ++i) af[i] = *(const s16x8*)(qptr[i] + off);
#pragma unroll
      for (int j = 0; j < 4; ++j) bf[j] = *(const s16x8*)(kptr[j] + off);
      __builtin_amdgcn_s_setprio(1);
#pragma unroll
      for (int i = 0; i < 2; ++i)
#pragma unroll
        for (int j = 0; j < 4; ++j) acc[i][j] = MFMA_BF16(af[i], bf[j], acc[i][j]);
      __builtin_amdgcn_s_setprio(0);
    }
  }

  const float scale = 0.04419417382415922f;  // 512^-0.5
  float rmax[2][4];
#pragma unroll
  for (int i = 0; i < 2; ++i) {
#pragma unroll
    for (int r = 0; r < 4; ++r) {
      const int qrow = qtr * 32 + i * 16 + quad * 4 + r;  // within-window row
      float mx = -3.4e38f;
#pragma unroll
      for (int j = 0; j < 4; ++j) {
        const int col = wn * 64 + j * 16 + nl;
        float v = acc[i][j][r] * scale;
        if (col >= 128 && col - 128 > qrow) v = -3.0e38f;  // causal mask
        if (w == 0 && col < 128) v = 0.0f;                 // zero bucket: sim=0
        acc[i][j][r] = v;
        mx = fmaxf(mx, v);
      }
      rmax[i][r] = mx;
    }
  }
#pragma unroll
  for (int off = 1; off < 16; off <<= 1)
#pragma unroll
    for (int i = 0; i < 2; ++i)
#pragma unroll
      for (int r = 0; r < 4; ++r)
        rmax[i][r] = fmaxf(rmax[i][r], __shfl_xor(rmax[i][r], off, 64));
  if (nl == 0) {
#pragma unroll
    for (int i = 0; i < 2; ++i)
#pragma unroll
      for (int r = 0; r < 4; ++r)
        redm[(i * 16 + quad * 4 + r) * 4 + wn] = rmax[i][r];
  }
  __syncthreads();
  float rsum[2][4];
#pragma unroll
  for (int i = 0; i < 2; ++i) {
#pragma unroll
    for (int r = 0; r < 4; ++r) {
      const f32x4 mv = *(const f32x4*)&redm[(i * 16 + quad * 4 + r) * 4];
      const float m = fmaxf(fmaxf(mv[0], mv[1]), fmaxf(mv[2], mv[3]));
      float s = 0.f;
#pragma unroll
      for (int j = 0; j < 4; ++j) {
        const float p = __expf(acc[i][j][r] - m);
        acc[i][j][r] = p;
        s += p;
      }
      rsum[i][r] = s;
    }
  }
#pragma unroll
  for (int off = 1; off < 16; off <<= 1)
#pragma unroll
    for (int i = 0; i < 2; ++i)
#pragma unroll
      for (int r = 0; r < 4; ++r) rsum[i][r] += __shfl_xor(rsum[i][r], off, 64);
  if (nl == 0) {
#pragma unroll
    for (int i = 0; i < 2; ++i)
#pragma unroll
      for (int r = 0; r < 4; ++r)
        reds[(i * 16 + quad * 4 + r) * 4 + wn] = rsum[i][r];
  }
  __syncthreads();
  // normalize, write P -> LDS (swizzled row-major 32x256 bf16)
#pragma unroll
  for (int i = 0; i < 2; ++i) {
#pragma unroll
    for (int r = 0; r < 4; ++r) {
      const int row = i * 16 + quad * 4 + r;
      const f32x4 sv = *(const f32x4*)&reds[row * 4];
      const float inv = 1.0f / (sv[0] + sv[1] + sv[2] + sv[3]);
#pragma unroll
      for (int j = 0; j < 4; ++j) {
        const int col = wn * 64 + j * 16 + nl;
        float pv = acc[i][j][r] * inv;
        if (w == 0 && col < 128) pv = 0.0f;  // zero V bucket
        const int cb = col >> 3;
        Ps[row * 256 + (((cb ^ (row & 7)) << 3) | (col & 7))] = f2bf(pv);
      }
    }
  }
  __syncthreads();

  // phase 2: out(32x512) = P(32x256) @ KWT-slice^T — B fragments direct from
  // L2 (KWT slice shared by the window's 4 blocks), no barriers in the loop.
  const int seqbase = w * 128 - 128;
#pragma unroll 1
  for (int och = 0; och < 4; ++och) {
    f32x4 acc2[2][2];
#pragma unroll
    for (int i = 0; i < 2; ++i)
#pragma unroll
      for (int j = 0; j < 2; ++j) acc2[i][j] = zero;
    const unsigned short* bp0 =
        KWT + (size_t)(b * 512 + och * 128 + wn * 32 + nl) * 8192;
    const unsigned short* bp1 = bp0 + (size_t)16 * 8192;
#pragma unroll
    for (int kch = 0; kch < 4; ++kch) {
#pragma unroll
      for (int ks = 0; ks < 2; ++ks) {
        int sq = seqbase + kch * 64 + (ks * 4 + quad) * 8;
        if (sq < 0) sq = 0;  // window 0: garbage seq hits zeroed P cols
        const int kb = kch * 8 + ks * 4 + quad;
        s16x8 af[2], bf[2];
#pragma unroll
        for (int i = 0; i < 2; ++i)
          af[i] = *(const s16x8*)&Ps[(i * 16 + nl) * 256 + ((kb ^ (nl & 7)) << 3)];
        bf[0] = *(const s16x8*)(bp0 + sq);
        bf[1] = *(const s16x8*)(bp1 + sq);
        __builtin_amdgcn_s_setprio(1);
#pragma unroll
        for (int i = 0; i < 2; ++i) {
          acc2[i][0] = MFMA_BF16(af[i], bf[0], acc2[i][0]);
          acc2[i][1] = MFMA_BF16(af[i], bf[1], acc2[i][1]);
        }
        __builtin_amdgcn_s_setprio(0);
      }
    }
#pragma unroll
    for (int i = 0; i < 2; ++i) {
      const int seq = w * 128 + qtr * 32 + i * 16 + quad * 4;
      float* dst = out + (size_t)(b * 8192 + seq) * 512;
#pragma unroll
      for (int j = 0; j < 2; ++j) {
        const int o = och * 128 + wn * 32 + j * 16 + nl;
        const float bo = bias[o];
#pragma unroll
        for (int r = 0; r < 4; ++r) dst[(size_t)r * 512 + o] = acc2[i][j][r] + bo;
      }
    }
  }
}

extern "C" void kernel_launch(void* const* d_in, const int* in_sizes, int n_in,
                              void* d_out, int out_size, void* d_ws, size_t ws_size,
                              hipStream_t stream) {
  const float* x = (const float*)d_in[0];
  const float* w_qkv = (const float*)d_in[1];
  const float* w_out = (const float*)d_in[2];
  const float* b_out = (const float*)d_in[3];
  float* out = (float*)d_out;

  char* ws = (char*)d_ws;
  // Layout (97.5 MB, within the 112 MB proven budget):
  //   Q   @  0  (32MB)
  //   K   @ 32M (32MB)
  //   xb  @ 64M (32MB)  dead after gemm_qk
  //   KWT @ 64M (32MB)  written by gemm_kwt (aliases xb)
  //   wb  @ 96M (1MB), wob @ 97M (0.5MB)
  unsigned short* Q = (unsigned short*)ws;
  unsigned short* K = (unsigned short*)(ws + (size_t)33554432);
  unsigned short* xb = (unsigned short*)(ws + (size_t)67108864);
  unsigned short* KWT = (unsigned short*)(ws + (size_t)67108864);
  unsigned short* wb = (unsigned short*)(ws + (size_t)100663296);
  unsigned short* wob = (unsigned short*)(ws + (size_t)100663296 + 1048576);

  cvt_bf16<<<dim3(8576), dim3(256), 0, stream>>>(x, w_qkv, w_out, xb, wb, wob);
  gemm_qk<<<dim3(2048), dim3(256), 0, stream>>>(xb, wb, Q, K);
  gemm_kwt<<<dim3(1024), dim3(256), 0, stream>>>(K, wob, KWT);
  attn64<<<dim3(1024), dim3(256), 0, stream>>>(Q, K, KWT, b_out, out);
}

// Round 3
// 245.159 us; speedup vs baseline: 1.1099x; 1.1099x over previous
//
#include <hip/hip_runtime.h>
#include <cstdint>
#include <cstddef>

typedef float f32x4 __attribute__((ext_vector_type(4)));
typedef short s16x8 __attribute__((ext_vector_type(8)));
typedef short s16x4 __attribute__((ext_vector_type(4)));

#define MFMA_BF16(a, b, c) __builtin_amdgcn_mfma_f32_16x16x32_bf16((a), (b), (c), 0, 0, 0)

// async global->LDS DMA, 16B/lane: lands at ldsbase + lane*16 (wave-uniform base)
#define GLD16(g, l)                                                            \
  __builtin_amdgcn_global_load_lds(                                            \
      (const __attribute__((address_space(1))) void*)(g),                      \
      (__attribute__((address_space(3))) void*)(l), 16, 0, 0)

__device__ __forceinline__ unsigned short f2bf(float f) {
  unsigned int u = __float_as_uint(f);
  u += 0x7FFFu + ((u >> 16) & 1u);
  return (unsigned short)(u >> 16);
}

__device__ __forceinline__ s16x8 cvt8(const float* __restrict__ src) {
  const float4 f0 = *(const float4*)src;
  const float4 f1 = *(const float4*)(src + 4);
  s16x8 h;
  h[0] = (short)f2bf(f0.x); h[1] = (short)f2bf(f0.y);
  h[2] = (short)f2bf(f0.z); h[3] = (short)f2bf(f0.w);
  h[4] = (short)f2bf(f1.x); h[5] = (short)f2bf(f1.y);
  h[6] = (short)f2bf(f1.z); h[7] = (short)f2bf(f1.w);
  return h;
}

// ---------------------------------------------------------------------------
// cvt_bf16: x -> xb, w_qkv[0:1024] -> wb (V-proj rows dead: reference builds
// v2 from k), w_out -> wob. Memory-bound one-shot.
// ---------------------------------------------------------------------------
#define XN 16777216   // 4*8192*512
#define WQN 524288    // 1024*512
__global__ __launch_bounds__(256)
void cvt_bf16(const float* __restrict__ x, const float* __restrict__ wqkv,
              const float* __restrict__ wout, unsigned short* __restrict__ xb,
              unsigned short* __restrict__ wb, unsigned short* __restrict__ wob) {
  const size_t i = (size_t)(blockIdx.x * 256 + threadIdx.x) * 8;
  const float* src;
  unsigned short* dst;
  if (i < XN) { src = x + i; dst = xb + i; }
  else if (i < XN + WQN) { src = wqkv + (i - XN); dst = wb + (i - XN); }
  else { src = wout + (i - XN - WQN); dst = wob + (i - XN - WQN); }
  *(s16x8*)dst = cvt8(src);
}

// ---------------------------------------------------------------------------
// gemm_qk: [Q|K] = xb @ wb^T. M=32768 N=1024 K=512. m97 structure, GLD16 both
// operands, XOR-swizzled LDS. SWAPPED staging: D transposed -> packed stores.
// ---------------------------------------------------------------------------
__global__ __launch_bounds__(256)
void gemm_qk(const unsigned short* __restrict__ xb, const unsigned short* __restrict__ wb,
             unsigned short* __restrict__ Q, unsigned short* __restrict__ K) {
  __shared__ unsigned short As[128 * 64];  // W tile
  __shared__ unsigned short Bs[128 * 64];  // x tile
  const int t = threadIdx.x, lane = t & 63, wid = t >> 6;
  const int wm = wid >> 1, wn = wid & 1;
  const int nl = lane & 15, quad = lane >> 4;
  const int sub = lane >> 3, lblk = (lane & 7) ^ sub;
  const int l = blockIdx.x;
  const int xcd = l & 7, g = l >> 3;
  const int mt = (g >> 3) * 8 + xcd, nt = g & 7;
  const int m0 = mt * 128, n0 = nt * 128;

  const f32x4 zero = {0.f, 0.f, 0.f, 0.f};
  f32x4 acc[4][4];
#pragma unroll
  for (int i = 0; i < 4; ++i)
#pragma unroll
    for (int j = 0; j < 4; ++j) acc[i][j] = zero;

  const unsigned short* gX = xb + (size_t)(m0 + wid * 32 + sub) * 512 + lblk * 8;
  const unsigned short* gW = wb + (size_t)(n0 + wid * 32 + sub) * 512 + lblk * 8;

  for (int kc = 0; kc < 512; kc += 64) {
#pragma unroll
    for (int ii = 0; ii < 4; ++ii) {
      GLD16(gW + kc + (size_t)(ii * 8) * 512, &As[(wid * 32 + ii * 8) * 64]);
      GLD16(gX + kc + (size_t)(ii * 8) * 512, &Bs[(wid * 32 + ii * 8) * 64]);
    }
    __syncthreads();
#pragma unroll
    for (int ks = 0; ks < 2; ++ks) {
      s16x8 af[4], bf[4];
#pragma unroll
      for (int i = 0; i < 4; ++i)
        af[i] = *(const s16x8*)&As[(wm * 64 + i * 16 + nl) * 64 +
                                   (((ks * 4 + quad) ^ (nl & 7)) * 8)];
#pragma unroll
      for (int j = 0; j < 4; ++j)
        bf[j] = *(const s16x8*)&Bs[(wn * 64 + j * 16 + nl) * 64 +
                                   (((ks * 4 + quad) ^ (nl & 7)) * 8)];
#pragma unroll
      for (int i = 0; i < 4; ++i)
#pragma unroll
        for (int j = 0; j < 4; ++j) acc[i][j] = MFMA_BF16(af[i], bf[j], acc[i][j]);
    }
    __syncthreads();
  }
#pragma unroll
  for (int i = 0; i < 4; ++i) {
    const int n = n0 + wm * 64 + i * 16 + quad * 4;
    unsigned short* base = (n < 512 ? Q : K);
    const int nn = n & 511;
#pragma unroll
    for (int j = 0; j < 4; ++j) {
      const int m = m0 + wn * 64 + j * 16 + nl;
      s16x4 h;
#pragma unroll
      for (int r = 0; r < 4; ++r) h[r] = (short)f2bf(acc[i][j][r]);
      *(s16x4*)&base[(size_t)m * 512 + nn] = h;
    }
  }
}

// ---------------------------------------------------------------------------
// gemm_kwt: KWT[b][o][seq] = (K @ wob^T)^T — output projection hoisted before
// attention. Normal operand order -> packed 8B transposed stores.
// ---------------------------------------------------------------------------
__global__ __launch_bounds__(256)
void gemm_kwt(const unsigned short* __restrict__ K, const unsigned short* __restrict__ wob,
              unsigned short* __restrict__ KWT) {
  __shared__ unsigned short As[128 * 64];
  __shared__ unsigned short Bs[128 * 64];
  const int t = threadIdx.x, lane = t & 63, wid = t >> 6;
  const int wm = wid >> 1, wn = wid & 1;
  const int nl = lane & 15, quad = lane >> 4;
  const int sub = lane >> 3, lblk = (lane & 7) ^ sub;
  const int l = blockIdx.x;
  const int xcd = l & 7, g = l >> 3;
  const int mt = (g >> 2) * 8 + xcd, nt = g & 3;
  const int m0 = mt * 128, n0 = nt * 128;

  const f32x4 zero = {0.f, 0.f, 0.f, 0.f};
  f32x4 acc[4][4];
#pragma unroll
  for (int i = 0; i < 4; ++i)
#pragma unroll
    for (int j = 0; j < 4; ++j) acc[i][j] = zero;

  const unsigned short* gA = K + (size_t)(m0 + wid * 32 + sub) * 512 + lblk * 8;
  const unsigned short* gB = wob + (size_t)(n0 + wid * 32 + sub) * 512 + lblk * 8;

  for (int kc = 0; kc < 512; kc += 64) {
#pragma unroll
    for (int ii = 0; ii < 4; ++ii) {
      GLD16(gA + kc + (size_t)(ii * 8) * 512, &As[(wid * 32 + ii * 8) * 64]);
      GLD16(gB + kc + (size_t)(ii * 8) * 512, &Bs[(wid * 32 + ii * 8) * 64]);
    }
    __syncthreads();
#pragma unroll
    for (int ks = 0; ks < 2; ++ks) {
      s16x8 af[4], bf[4];
#pragma unroll
      for (int i = 0; i < 4; ++i)
        af[i] = *(const s16x8*)&As[(wm * 64 + i * 16 + nl) * 64 +
                                   (((ks * 4 + quad) ^ (nl & 7)) * 8)];
#pragma unroll
      for (int j = 0; j < 4; ++j)
        bf[j] = *(const s16x8*)&Bs[(wn * 64 + j * 16 + nl) * 64 +
                                   (((ks * 4 + quad) ^ (nl & 7)) * 8)];
#pragma unroll
      for (int i = 0; i < 4; ++i)
#pragma unroll
        for (int j = 0; j < 4; ++j) acc[i][j] = MFMA_BF16(af[i], bf[j], acc[i][j]);
    }
    __syncthreads();
  }
#pragma unroll
  for (int i = 0; i < 4; ++i) {
    const int ms = m0 + wm * 64 + i * 16 + quad * 4;
    const int b = ms >> 13, ns = ms & 8191;
#pragma unroll
    for (int j = 0; j < 4; ++j) {
      const int o = n0 + wn * 64 + j * 16 + nl;
      s16x4 h;
#pragma unroll
      for (int r = 0; r < 4; ++r) h[r] = (short)f2bf(acc[i][j][r]);
      *(s16x4*)&KWT[(size_t)(b * 512 + o) * 8192 + ns] = h;
    }
  }
}

// ---------------------------------------------------------------------------
// attn64 v4: 64 Q-rows/block, grid 512, 2 blocks/CU (LDS 80KB). Round-2
// proved the bottleneck is per-wave MLP, not occupancy/barriers. Fix: T3+T4 —
// GLD16 staging (VGPR-free in-flight bytes) + double-buffered prefetch +
// COUNTED s_waitcnt vmcnt(N) + raw s_barrier (never __syncthreads in loops:
// it drains vmcnt(0) and kills the pipeline). In-flight 40KB/block sustained.
// Phase-2 KWT chunks prefetched depth-2 starting inside phase 1, so softmax
// VALU time covers memory. LDS aliasing (Ps/redm/reds over dead phase-1
// buffers) is barrier-protected; vmcnt counts are uniform across waves.
// ---------------------------------------------------------------------------
__global__ __launch_bounds__(256)
void attn64(const unsigned short* __restrict__ Q, const unsigned short* __restrict__ K,
            const unsigned short* __restrict__ KWT, const float* __restrict__ bias,
            float* __restrict__ out) {
  __shared__ __align__(16) char smem[81920];
  unsigned short* const Qb0 = (unsigned short*)smem;            // 8KB  [0,8K)
  unsigned short* const Qb1 = (unsigned short*)(smem + 8192);   // 8KB  [8K,16K)
  unsigned short* const Kb0 = (unsigned short*)(smem + 16384);  // 32KB [16K,48K)
  unsigned short* const Kb1 = (unsigned short*)(smem + 49152);  // 32KB [48K,80K)
  float* const redm = (float*)(smem + 8192);                    // 1KB alias Qb1 (dead post-phase1)
  float* const reds = (float*)(smem + 9216);                    // 1KB alias Qb1
  unsigned short* const Ps = (unsigned short*)smem;             // 32KB [0,32K) phase2
  unsigned short* const B20 = (unsigned short*)(smem + 32768);  // 16KB alias Kb0-top (dead after s=6)
  unsigned short* const B21 = (unsigned short*)(smem + 49152);  // 16KB alias Kb1-bottom (dead after s=7)

  const int t = threadIdx.x, lane = t & 63, wid = t >> 6;
  const int wn = wid;  // 4 waves split the 256 sim cols
  const int nl = lane & 15, quad = lane >> 4;
  const int sub = lane >> 3, lblk = (lane & 7) ^ sub;
  // paired-XCD decode: bx = g*16 + half*8 + xcd
  const int bx = blockIdx.x;
  const int xcd = bx & 7, half = (bx >> 3) & 1, g = bx >> 4;
  const int wb = g * 8 + xcd, b = wb >> 6, w = wb & 63;

  const unsigned short* Qg = Q + (size_t)(b * 8192 + w * 128 + half * 64) * 512;
  const unsigned short* Kg = K + (size_t)(b * 8192) * 512;
  const unsigned short* KWTb = KWT + (size_t)(b * 512) * 8192;
  const int seqbase = w * 128 - 128;

// stage one phase-1 K-chunk (kc column chunk kcc): 10 GLD16/wave, uniform
#define STAGE_P1(kcc, qb, kb)                                                  \
  do {                                                                         \
    _Pragma("unroll") for (int ii = 0; ii < 2; ++ii)                           \
        GLD16(Qg + (size_t)(wid * 16 + ii * 8 + sub) * 512 + (kcc) + lblk * 8, \
              (qb) + (wid * 16 + ii * 8) * 64);                                \
    _Pragma("unroll") for (int ii = 0; ii < 8; ++ii) {                         \
      int sq_ = seqbase + wid * 64 + ii * 8 + sub;                             \
      if (sq_ < 0) sq_ = 0;                                                    \
      GLD16(Kg + (size_t)sq_ * 512 + (kcc) + lblk * 8,                         \
            (kb) + (wid * 64 + ii * 8) * 64);                                  \
    }                                                                          \
  } while (0)

// stage one phase-2 KWT chunk (tile tt: och=tt>>2, kch=tt&3): 4 GLD16/wave
#define STAGE_B2(tt, bb)                                                       \
  do {                                                                         \
    const int och_ = (tt) >> 2, kch_ = (tt) & 3;                               \
    int sq_ = seqbase + kch_ * 64 + lblk * 8;                                  \
    if (sq_ < 0) sq_ = 0;                                                      \
    _Pragma("unroll") for (int ii = 0; ii < 4; ++ii)                           \
        GLD16(KWTb + (size_t)(och_ * 128 + wid * 32 + ii * 8 + sub) * 8192 + sq_, \
              (bb) + (wid * 32 + ii * 8) * 64);                                \
  } while (0)

  // preload bias (keeps the mid-loop vmem stream = staging only)
  float bo[4][2];
#pragma unroll
  for (int och = 0; och < 4; ++och)
#pragma unroll
    for (int j = 0; j < 2; ++j) bo[och][j] = bias[och * 128 + wn * 32 + j * 16 + nl];

  const f32x4 zero = {0.f, 0.f, 0.f, 0.f};
  f32x4 acc[4][4];
#pragma unroll
  for (int i = 0; i < 4; ++i)
#pragma unroll
    for (int j = 0; j < 4; ++j) acc[i][j] = zero;

  // ---- phase 1: sim = Q.K2^T, double-buffered counted-vmcnt pipeline ----
  STAGE_P1(0, Qb0, Kb0);
#pragma unroll
  for (int s = 0; s < 8; ++s) {
    unsigned short* const qb = (s & 1) ? Qb1 : Qb0;
    unsigned short* const kb = (s & 1) ? Kb1 : Kb0;
    if (s < 7) {
      STAGE_P1((s + 1) * 64, (s & 1) ? Qb0 : Qb1, (s & 1) ? Kb0 : Kb1);
      asm volatile("s_waitcnt vmcnt(10)" ::: "memory");  // tile s ready, s+1 in flight
    } else {
      STAGE_B2(0, B20);  // phase-2 prefetch depth begins here
      asm volatile("s_waitcnt vmcnt(4)" ::: "memory");
    }
    __builtin_amdgcn_s_barrier();
    asm volatile("" ::: "memory");
#pragma unroll
    for (int ks = 0; ks < 2; ++ks) {
      s16x8 af[4], bf[4];
#pragma unroll
      for (int i = 0; i < 4; ++i)
        af[i] = *(const s16x8*)&qb[(i * 16 + nl) * 64 +
                                   (((ks * 4 + quad) ^ (nl & 7)) * 8)];
#pragma unroll
      for (int j = 0; j < 4; ++j)
        bf[j] = *(const s16x8*)&kb[(wn * 64 + j * 16 + nl) * 64 +
                                   (((ks * 4 + quad) ^ (nl & 7)) * 8)];
      __builtin_amdgcn_s_setprio(1);
#pragma unroll
      for (int i = 0; i < 4; ++i)
#pragma unroll
        for (int j = 0; j < 4; ++j) acc[i][j] = MFMA_BF16(af[i], bf[j], acc[i][j]);
      __builtin_amdgcn_s_setprio(0);
    }
    asm volatile("" ::: "memory");
    __builtin_amdgcn_s_barrier();
  }
  STAGE_B2(1, B21);  // second phase-2 chunk rides under softmax

  // ---- softmax (raw barriers; no vmcnt drains) ----
  const float scale = 0.04419417382415922f;  // 512^-0.5
  float rmax[4][4];
#pragma unroll
  for (int i = 0; i < 4; ++i) {
#pragma unroll
    for (int r = 0; r < 4; ++r) {
      const int qrow = half * 64 + i * 16 + quad * 4 + r;  // within-window row
      float mx = -3.4e38f;
#pragma unroll
      for (int j = 0; j < 4; ++j) {
        const int col = wn * 64 + j * 16 + nl;
        float v = acc[i][j][r] * scale;
        if (col >= 128 && col - 128 > qrow) v = -3.0e38f;  // causal mask
        if (w == 0 && col < 128) v = 0.0f;                 // zero bucket: sim=0
        acc[i][j][r] = v;
        mx = fmaxf(mx, v);
      }
      rmax[i][r] = mx;
    }
  }
#pragma unroll
  for (int off = 1; off < 16; off <<= 1)
#pragma unroll
    for (int i = 0; i < 4; ++i)
#pragma unroll
      for (int r = 0; r < 4; ++r)
        rmax[i][r] = fmaxf(rmax[i][r], __shfl_xor(rmax[i][r], off, 64));
  if (nl == 0) {
#pragma unroll
    for (int i = 0; i < 4; ++i)
#pragma unroll
      for (int r = 0; r < 4; ++r)
        redm[(i * 16 + quad * 4 + r) * 4 + wn] = rmax[i][r];
  }
  asm volatile("s_waitcnt lgkmcnt(0)" ::: "memory");
  __builtin_amdgcn_s_barrier();
  asm volatile("" ::: "memory");
  float rsum[4][4];
#pragma unroll
  for (int i = 0; i < 4; ++i) {
#pragma unroll
    for (int r = 0; r < 4; ++r) {
      const f32x4 mv = *(const f32x4*)&redm[(i * 16 + quad * 4 + r) * 4];
      const float m = fmaxf(fmaxf(mv[0], mv[1]), fmaxf(mv[2], mv[3]));
      float s = 0.f;
#pragma unroll
      for (int j = 0; j < 4; ++j) {
        const float p = __expf(acc[i][j][r] - m);
        acc[i][j][r] = p;
        s += p;
      }
      rsum[i][r] = s;
    }
  }
#pragma unroll
  for (int off = 1; off < 16; off <<= 1)
#pragma unroll
    for (int i = 0; i < 4; ++i)
#pragma unroll
      for (int r = 0; r < 4; ++r) rsum[i][r] += __shfl_xor(rsum[i][r], off, 64);
  if (nl == 0) {
#pragma unroll
    for (int i = 0; i < 4; ++i)
#pragma unroll
      for (int r = 0; r < 4; ++r)
        reds[(i * 16 + quad * 4 + r) * 4 + wn] = rsum[i][r];
  }
  asm volatile("s_waitcnt lgkmcnt(0)" ::: "memory");
  __builtin_amdgcn_s_barrier();
  asm volatile("" ::: "memory");
  // precompute 1/sum BEFORE Ps overwrites reds (aliased) — then barrier
  float invv[4][4];
#pragma unroll
  for (int i = 0; i < 4; ++i)
#pragma unroll
    for (int r = 0; r < 4; ++r) {
      const f32x4 sv = *(const f32x4*)&reds[(i * 16 + quad * 4 + r) * 4];
      invv[i][r] = 1.0f / (sv[0] + sv[1] + sv[2] + sv[3]);
    }
  asm volatile("s_waitcnt lgkmcnt(0)" ::: "memory");
  __builtin_amdgcn_s_barrier();
  asm volatile("" ::: "memory");
  // normalize, write P -> LDS (swizzled row-major 64x256 bf16)
#pragma unroll
  for (int i = 0; i < 4; ++i) {
#pragma unroll
    for (int r = 0; r < 4; ++r) {
      const int row = i * 16 + quad * 4 + r;
#pragma unroll
      for (int j = 0; j < 4; ++j) {
        const int col = wn * 64 + j * 16 + nl;
        float pv = acc[i][j][r] * invv[i][r];
        if (w == 0 && col < 128) pv = 0.0f;  // zero V bucket
        const int cb = col >> 3;
        Ps[row * 256 + (((cb ^ (row & 7)) << 3) | (col & 7))] = f2bf(pv);
      }
    }
  }
  asm volatile("s_waitcnt lgkmcnt(0)" ::: "memory");
  __builtin_amdgcn_s_barrier();
  asm volatile("" ::: "memory");

  // ---- phase 2: out = P @ KWT^T, depth-2 prefetched counted-vmcnt ----
  f32x4 acc2[4][2];
#pragma unroll
  for (int t2 = 0; t2 < 16; ++t2) {
    const int och = t2 >> 2, kch = t2 & 3;
    unsigned short* const bb = (t2 & 1) ? B21 : B20;
    if (kch == 0) {
#pragma unroll
      for (int i = 0; i < 4; ++i)
#pragma unroll
        for (int j = 0; j < 2; ++j) acc2[i][j] = zero;
    }
    if (t2 < 15) asm volatile("s_waitcnt vmcnt(4)" ::: "memory");
    else         asm volatile("s_waitcnt vmcnt(0)" ::: "memory");
    __builtin_amdgcn_s_barrier();
    asm volatile("" ::: "memory");
#pragma unroll
    for (int ks = 0; ks < 2; ++ks) {
      const int kb2 = kch * 8 + ks * 4 + quad;
      s16x8 af[4], bf[2];
#pragma unroll
      for (int i = 0; i < 4; ++i)
        af[i] = *(const s16x8*)&Ps[(i * 16 + nl) * 256 + ((kb2 ^ (nl & 7)) << 3)];
#pragma unroll
      for (int j = 0; j < 2; ++j)
        bf[j] = *(const s16x8*)&bb[(wn * 32 + j * 16 + nl) * 64 +
                                   (((ks * 4 + quad) ^ (nl & 7)) * 8)];
      __builtin_amdgcn_s_setprio(1);
#pragma unroll
      for (int i = 0; i < 4; ++i) {
        acc2[i][0] = MFMA_BF16(af[i], bf[0], acc2[i][0]);
        acc2[i][1] = MFMA_BF16(af[i], bf[1], acc2[i][1]);
      }
      __builtin_amdgcn_s_setprio(0);
    }
    asm volatile("" ::: "memory");
    __builtin_amdgcn_s_barrier();
    if (kch == 3) {
#pragma unroll
      for (int i = 0; i < 4; ++i) {
        const int seq = w * 128 + half * 64 + i * 16 + quad * 4;
        float* dst = out + (size_t)(b * 8192 + seq) * 512;
#pragma unroll
        for (int j = 0; j < 2; ++j) {
          const int o = och * 128 + wn * 32 + j * 16 + nl;
#pragma unroll
          for (int r = 0; r < 4; ++r) dst[(size_t)r * 512 + o] = acc2[i][j][r] + bo[och][j];
        }
      }
    }
    if (t2 < 14) STAGE_B2(t2 + 2, bb);  // refill the buffer just consumed
  }
#undef STAGE_P1
#undef STAGE_B2
}

extern "C" void kernel_launch(void* const* d_in, const int* in_sizes, int n_in,
                              void* d_out, int out_size, void* d_ws, size_t ws_size,
                              hipStream_t stream) {
  const float* x = (const float*)d_in[0];
  const float* w_qkv = (const float*)d_in[1];
  const float* w_out = (const float*)d_in[2];
  const float* b_out = (const float*)d_in[3];
  float* out = (float*)d_out;

  char* ws = (char*)d_ws;
  // Layout (97.5 MB, within the 112 MB proven budget):
  //   Q   @  0  (32MB)
  //   K   @ 32M (32MB)
  //   xb  @ 64M (32MB)  dead after gemm_qk
  //   KWT @ 64M (32MB)  written by gemm_kwt (aliases xb)
  //   wb  @ 96M (1MB), wob @ 97M (0.5MB)
  unsigned short* Q = (unsigned short*)ws;
  unsigned short* K = (unsigned short*)(ws + (size_t)33554432);
  unsigned short* xb = (unsigned short*)(ws + (size_t)67108864);
  unsigned short* KWT = (unsigned short*)(ws + (size_t)67108864);
  unsigned short* wb = (unsigned short*)(ws + (size_t)100663296);
  unsigned short* wob = (unsigned short*)(ws + (size_t)100663296 + 1048576);

  cvt_bf16<<<dim3(8576), dim3(256), 0, stream>>>(x, w_qkv, w_out, xb, wb, wob);
  gemm_qk<<<dim3(2048), dim3(256), 0, stream>>>(xb, wb, Q, K);
  gemm_kwt<<<dim3(1024), dim3(256), 0, stream>>>(K, wob, KWT);
  attn64<<<dim3(512), dim3(256), 0, stream>>>(Q, K, KWT, b_out, out);
}

// Round 4
// 230.815 us; speedup vs baseline: 1.1789x; 1.0621x over previous
//
#include <hip/hip_runtime.h>
#include <cstdint>
#include <cstddef>

typedef float f32x4 __attribute__((ext_vector_type(4)));
typedef short s16x8 __attribute__((ext_vector_type(8)));
typedef short s16x4 __attribute__((ext_vector_type(4)));

#define MFMA_BF16(a, b, c) __builtin_amdgcn_mfma_f32_16x16x32_bf16((a), (b), (c), 0, 0, 0)

// async global->LDS DMA, 16B/lane: lands at ldsbase + lane*16 (wave-uniform base)
#define GLD16(g, l)                                                            \
  __builtin_amdgcn_global_load_lds(                                            \
      (const __attribute__((address_space(1))) void*)(g),                      \
      (__attribute__((address_space(3))) void*)(l), 16, 0, 0)

__device__ __forceinline__ unsigned short f2bf(float f) {
  unsigned int u = __float_as_uint(f);
  u += 0x7FFFu + ((u >> 16) & 1u);
  return (unsigned short)(u >> 16);
}

__device__ __forceinline__ s16x8 cvt8(const float* __restrict__ src) {
  const float4 f0 = *(const float4*)src;
  const float4 f1 = *(const float4*)(src + 4);
  s16x8 h;
  h[0] = (short)f2bf(f0.x); h[1] = (short)f2bf(f0.y);
  h[2] = (short)f2bf(f0.z); h[3] = (short)f2bf(f0.w);
  h[4] = (short)f2bf(f1.x); h[5] = (short)f2bf(f1.y);
  h[6] = (short)f2bf(f1.z); h[7] = (short)f2bf(f1.w);
  return h;
}

// ---------------------------------------------------------------------------
// cvt_bf16: x -> xb, w_qkv[0:1024] -> wb (V-proj rows dead: reference builds
// v2 from k), w_out -> wob. Memory-bound one-shot.
// ---------------------------------------------------------------------------
#define XN 16777216   // 4*8192*512
#define WQN 524288    // 1024*512
__global__ __launch_bounds__(256)
void cvt_bf16(const float* __restrict__ x, const float* __restrict__ wqkv,
              const float* __restrict__ wout, unsigned short* __restrict__ xb,
              unsigned short* __restrict__ wb, unsigned short* __restrict__ wob) {
  const size_t i = (size_t)(blockIdx.x * 256 + threadIdx.x) * 8;
  const float* src;
  unsigned short* dst;
  if (i < XN) { src = x + i; dst = xb + i; }
  else if (i < XN + WQN) { src = wqkv + (i - XN); dst = wb + (i - XN); }
  else { src = wout + (i - XN - WQN); dst = wob + (i - XN - WQN); }
  *(s16x8*)dst = cvt8(src);
}

// ---------------------------------------------------------------------------
// gemm_qk: [Q|K] = xb @ wb^T. M=32768 N=1024 K=512. m97 structure, GLD16 both
// operands, XOR-swizzled LDS. SWAPPED staging: D transposed -> packed stores.
// ---------------------------------------------------------------------------
__global__ __launch_bounds__(256)
void gemm_qk(const unsigned short* __restrict__ xb, const unsigned short* __restrict__ wb,
             unsigned short* __restrict__ Q, unsigned short* __restrict__ K) {
  __shared__ unsigned short As[128 * 64];  // W tile
  __shared__ unsigned short Bs[128 * 64];  // x tile
  const int t = threadIdx.x, lane = t & 63, wid = t >> 6;
  const int wm = wid >> 1, wn = wid & 1;
  const int nl = lane & 15, quad = lane >> 4;
  const int sub = lane >> 3, lblk = (lane & 7) ^ sub;
  const int l = blockIdx.x;
  const int xcd = l & 7, g = l >> 3;
  const int mt = (g >> 3) * 8 + xcd, nt = g & 7;
  const int m0 = mt * 128, n0 = nt * 128;

  const f32x4 zero = {0.f, 0.f, 0.f, 0.f};
  f32x4 acc[4][4];
#pragma unroll
  for (int i = 0; i < 4; ++i)
#pragma unroll
    for (int j = 0; j < 4; ++j) acc[i][j] = zero;

  const unsigned short* gX = xb + (size_t)(m0 + wid * 32 + sub) * 512 + lblk * 8;
  const unsigned short* gW = wb + (size_t)(n0 + wid * 32 + sub) * 512 + lblk * 8;

  for (int kc = 0; kc < 512; kc += 64) {
#pragma unroll
    for (int ii = 0; ii < 4; ++ii) {
      GLD16(gW + kc + (size_t)(ii * 8) * 512, &As[(wid * 32 + ii * 8) * 64]);
      GLD16(gX + kc + (size_t)(ii * 8) * 512, &Bs[(wid * 32 + ii * 8) * 64]);
    }
    __syncthreads();
#pragma unroll
    for (int ks = 0; ks < 2; ++ks) {
      s16x8 af[4], bf[4];
#pragma unroll
      for (int i = 0; i < 4; ++i)
        af[i] = *(const s16x8*)&As[(wm * 64 + i * 16 + nl) * 64 +
                                   (((ks * 4 + quad) ^ (nl & 7)) * 8)];
#pragma unroll
      for (int j = 0; j < 4; ++j)
        bf[j] = *(const s16x8*)&Bs[(wn * 64 + j * 16 + nl) * 64 +
                                   (((ks * 4 + quad) ^ (nl & 7)) * 8)];
#pragma unroll
      for (int i = 0; i < 4; ++i)
#pragma unroll
        for (int j = 0; j < 4; ++j) acc[i][j] = MFMA_BF16(af[i], bf[j], acc[i][j]);
    }
    __syncthreads();
  }
#pragma unroll
  for (int i = 0; i < 4; ++i) {
    const int n = n0 + wm * 64 + i * 16 + quad * 4;
    unsigned short* base = (n < 512 ? Q : K);
    const int nn = n & 511;
#pragma unroll
    for (int j = 0; j < 4; ++j) {
      const int m = m0 + wn * 64 + j * 16 + nl;
      s16x4 h;
#pragma unroll
      for (int r = 0; r < 4; ++r) h[r] = (short)f2bf(acc[i][j][r]);
      *(s16x4*)&base[(size_t)m * 512 + nn] = h;
    }
  }
}

// ---------------------------------------------------------------------------
// gemm_kwt: KWT[b][o][seq] = (K @ wob^T)^T — output projection hoisted before
// attention. Normal operand order -> packed 8B transposed stores.
// ---------------------------------------------------------------------------
__global__ __launch_bounds__(256)
void gemm_kwt(const unsigned short* __restrict__ K, const unsigned short* __restrict__ wob,
              unsigned short* __restrict__ KWT) {
  __shared__ unsigned short As[128 * 64];
  __shared__ unsigned short Bs[128 * 64];
  const int t = threadIdx.x, lane = t & 63, wid = t >> 6;
  const int wm = wid >> 1, wn = wid & 1;
  const int nl = lane & 15, quad = lane >> 4;
  const int sub = lane >> 3, lblk = (lane & 7) ^ sub;
  const int l = blockIdx.x;
  const int xcd = l & 7, g = l >> 3;
  const int mt = (g >> 2) * 8 + xcd, nt = g & 3;
  const int m0 = mt * 128, n0 = nt * 128;

  const f32x4 zero = {0.f, 0.f, 0.f, 0.f};
  f32x4 acc[4][4];
#pragma unroll
  for (int i = 0; i < 4; ++i)
#pragma unroll
    for (int j = 0; j < 4; ++j) acc[i][j] = zero;

  const unsigned short* gA = K + (size_t)(m0 + wid * 32 + sub) * 512 + lblk * 8;
  const unsigned short* gB = wob + (size_t)(n0 + wid * 32 + sub) * 512 + lblk * 8;

  for (int kc = 0; kc < 512; kc += 64) {
#pragma unroll
    for (int ii = 0; ii < 4; ++ii) {
      GLD16(gA + kc + (size_t)(ii * 8) * 512, &As[(wid * 32 + ii * 8) * 64]);
      GLD16(gB + kc + (size_t)(ii * 8) * 512, &Bs[(wid * 32 + ii * 8) * 64]);
    }
    __syncthreads();
#pragma unroll
    for (int ks = 0; ks < 2; ++ks) {
      s16x8 af[4], bf[4];
#pragma unroll
      for (int i = 0; i < 4; ++i)
        af[i] = *(const s16x8*)&As[(wm * 64 + i * 16 + nl) * 64 +
                                   (((ks * 4 + quad) ^ (nl & 7)) * 8)];
#pragma unroll
      for (int j = 0; j < 4; ++j)
        bf[j] = *(const s16x8*)&Bs[(wn * 64 + j * 16 + nl) * 64 +
                                   (((ks * 4 + quad) ^ (nl & 7)) * 8)];
#pragma unroll
      for (int i = 0; i < 4; ++i)
#pragma unroll
        for (int j = 0; j < 4; ++j) acc[i][j] = MFMA_BF16(af[i], bf[j], acc[i][j]);
    }
    __syncthreads();
  }
#pragma unroll
  for (int i = 0; i < 4; ++i) {
    const int ms = m0 + wm * 64 + i * 16 + quad * 4;
    const int b = ms >> 13, ns = ms & 8191;
#pragma unroll
    for (int j = 0; j < 4; ++j) {
      const int o = n0 + wn * 64 + j * 16 + nl;
      s16x4 h;
#pragma unroll
      for (int r = 0; r < 4; ++r) h[r] = (short)f2bf(acc[i][j][r]);
      *(s16x4*)&KWT[(size_t)(b * 512 + o) * 8192 + ns] = h;
    }
  }
}

// ---------------------------------------------------------------------------
// attn64 v5: phase 1 = R3's proven dbuf counted-vmcnt pipeline (barriers
// needed: Q staging is cross-wave). Phase 2 REWRITTEN barrier-free: KWT
// staging is wave-self-contained (wave wn stages+reads only rows wn*32..+32),
// Ps is read-only after one publish barrier -> free-running per-wave 3-deep
// pipeline with hand-counted vmcnt (out-stores, 32/och-group, included in the
// in-order queue: waits {8,8,8,8,40,40,8,8,40,40,8,8,40,40,4,0}). B2 chunks
// 0-2 issued before softmax (aliased K regions dead after the loop's trailing
// barrier), so softmax VALU time covers their flight.
// ---------------------------------------------------------------------------
__global__ __launch_bounds__(256)
void attn64(const unsigned short* __restrict__ Q, const unsigned short* __restrict__ K,
            const unsigned short* __restrict__ KWT, const float* __restrict__ bias,
            float* __restrict__ out) {
  __shared__ __align__(16) char smem[81920];
  unsigned short* const Qb0 = (unsigned short*)smem;            // 8KB  [0,8K)
  unsigned short* const Qb1 = (unsigned short*)(smem + 8192);   // 8KB  [8K,16K)
  unsigned short* const Kb0 = (unsigned short*)(smem + 16384);  // 32KB [16K,48K)
  unsigned short* const Kb1 = (unsigned short*)(smem + 49152);  // 32KB [48K,80K)
  float* const redm = (float*)(smem + 8192);                    // 1KB alias Qb1 (dead post-phase1)
  float* const reds = (float*)(smem + 9216);                    // 1KB alias Qb1
  unsigned short* const Ps = (unsigned short*)smem;             // 32KB [0,32K) phase2
  // phase-2 KWT buffers: 3 x 16KB at [32K,80K) (alias Kb0-top / Kb1)
#define B2BUF(n) ((unsigned short*)(smem + 32768 + (n) * 16384))

  const int t = threadIdx.x, lane = t & 63, wid = t >> 6;
  const int wn = wid;  // 4 waves split the 256 sim cols
  const int nl = lane & 15, quad = lane >> 4;
  const int sub = lane >> 3, lblk = (lane & 7) ^ sub;
  // paired-XCD decode: bx = g*16 + half*8 + xcd
  const int bx = blockIdx.x;
  const int xcd = bx & 7, half = (bx >> 3) & 1, g = bx >> 4;
  const int wb = g * 8 + xcd, b = wb >> 6, w = wb & 63;

  const unsigned short* Qg = Q + (size_t)(b * 8192 + w * 128 + half * 64) * 512;
  const unsigned short* Kg = K + (size_t)(b * 8192) * 512;
  const unsigned short* KWTb = KWT + (size_t)(b * 512) * 8192;
  const int seqbase = w * 128 - 128;

// stage one phase-1 K-chunk (kc column chunk kcc): 10 GLD16/wave, uniform
#define STAGE_P1(kcc, qb, kb)                                                  \
  do {                                                                         \
    _Pragma("unroll") for (int ii = 0; ii < 2; ++ii)                           \
        GLD16(Qg + (size_t)(wid * 16 + ii * 8 + sub) * 512 + (kcc) + lblk * 8, \
              (qb) + (wid * 16 + ii * 8) * 64);                                \
    _Pragma("unroll") for (int ii = 0; ii < 8; ++ii) {                         \
      int sq_ = seqbase + wid * 64 + ii * 8 + sub;                             \
      if (sq_ < 0) sq_ = 0;                                                    \
      GLD16(Kg + (size_t)sq_ * 512 + (kcc) + lblk * 8,                         \
            (kb) + (wid * 64 + ii * 8) * 64);                                  \
    }                                                                          \
  } while (0)

// stage one phase-2 KWT chunk (tile tt: och=tt>>2, kch=tt&3): 4 GLD16/wave,
// writes ONLY this wave's rows wid*32..+32 of the buffer (self-contained)
#define STAGE_B2(tt, bb)                                                       \
  do {                                                                         \
    const int och_ = (tt) >> 2, kch_ = (tt) & 3;                               \
    int sq_ = seqbase + kch_ * 64 + lblk * 8;                                  \
    if (sq_ < 0) sq_ = 0;                                                      \
    _Pragma("unroll") for (int ii = 0; ii < 4; ++ii)                           \
        GLD16(KWTb + (size_t)(och_ * 128 + wid * 32 + ii * 8 + sub) * 8192 + sq_, \
              (bb) + (wid * 32 + ii * 8) * 64);                                \
  } while (0)

  // preload bias (before any asm clobber: stays put, retired by first wait)
  float bo[4][2];
#pragma unroll
  for (int och = 0; och < 4; ++och)
#pragma unroll
    for (int j = 0; j < 2; ++j) bo[och][j] = bias[och * 128 + wn * 32 + j * 16 + nl];

  const f32x4 zero = {0.f, 0.f, 0.f, 0.f};
  f32x4 acc[4][4];
#pragma unroll
  for (int i = 0; i < 4; ++i)
#pragma unroll
    for (int j = 0; j < 4; ++j) acc[i][j] = zero;

  // ---- phase 1: sim = Q.K2^T, double-buffered counted-vmcnt pipeline ----
  STAGE_P1(0, Qb0, Kb0);
#pragma unroll
  for (int s = 0; s < 8; ++s) {
    unsigned short* const qb = (s & 1) ? Qb1 : Qb0;
    unsigned short* const kb = (s & 1) ? Kb1 : Kb0;
    if (s < 7) {
      STAGE_P1((s + 1) * 64, (s & 1) ? Qb0 : Qb1, (s & 1) ? Kb0 : Kb1);
      asm volatile("s_waitcnt vmcnt(10)" ::: "memory");  // tile s ready, s+1 in flight
    } else {
      STAGE_B2(0, B2BUF(0));  // phase-2 prefetch depth begins here
      asm volatile("s_waitcnt vmcnt(4)" ::: "memory");
    }
    __builtin_amdgcn_s_barrier();
    asm volatile("" ::: "memory");
#pragma unroll
    for (int ks = 0; ks < 2; ++ks) {
      s16x8 af[4], bf[4];
#pragma unroll
      for (int i = 0; i < 4; ++i)
        af[i] = *(const s16x8*)&qb[(i * 16 + nl) * 64 +
                                   (((ks * 4 + quad) ^ (nl & 7)) * 8)];
#pragma unroll
      for (int j = 0; j < 4; ++j)
        bf[j] = *(const s16x8*)&kb[(wn * 64 + j * 16 + nl) * 64 +
                                   (((ks * 4 + quad) ^ (nl & 7)) * 8)];
      __builtin_amdgcn_s_setprio(1);
#pragma unroll
      for (int i = 0; i < 4; ++i)
#pragma unroll
        for (int j = 0; j < 4; ++j) acc[i][j] = MFMA_BF16(af[i], bf[j], acc[i][j]);
      __builtin_amdgcn_s_setprio(0);
    }
    asm volatile("" ::: "memory");
    __builtin_amdgcn_s_barrier();
  }
  // trailing barrier of s==7 just passed: ALL phase-1 LDS reads done ->
  // aliased regions (Kb1) are dead; issue B2 chunks 1,2 to fly under softmax.
  STAGE_B2(1, B2BUF(1));
  STAGE_B2(2, B2BUF(2));

  // ---- softmax (raw barriers; no vmcnt drains) ----
  const float scale = 0.04419417382415922f;  // 512^-0.5
  float rmax[4][4];
#pragma unroll
  for (int i = 0; i < 4; ++i) {
#pragma unroll
    for (int r = 0; r < 4; ++r) {
      const int qrow = half * 64 + i * 16 + quad * 4 + r;  // within-window row
      float mx = -3.4e38f;
#pragma unroll
      for (int j = 0; j < 4; ++j) {
        const int col = wn * 64 + j * 16 + nl;
        float v = acc[i][j][r] * scale;
        if (col >= 128 && col - 128 > qrow) v = -3.0e38f;  // causal mask
        if (w == 0 && col < 128) v = 0.0f;                 // zero bucket: sim=0
        acc[i][j][r] = v;
        mx = fmaxf(mx, v);
      }
      rmax[i][r] = mx;
    }
  }
#pragma unroll
  for (int off = 1; off < 16; off <<= 1)
#pragma unroll
    for (int i = 0; i < 4; ++i)
#pragma unroll
      for (int r = 0; r < 4; ++r)
        rmax[i][r] = fmaxf(rmax[i][r], __shfl_xor(rmax[i][r], off, 64));
  if (nl == 0) {
#pragma unroll
    for (int i = 0; i < 4; ++i)
#pragma unroll
      for (int r = 0; r < 4; ++r)
        redm[(i * 16 + quad * 4 + r) * 4 + wn] = rmax[i][r];
  }
  asm volatile("s_waitcnt lgkmcnt(0)" ::: "memory");
  __builtin_amdgcn_s_barrier();
  asm volatile("" ::: "memory");
  float rsum[4][4];
#pragma unroll
  for (int i = 0; i < 4; ++i) {
#pragma unroll
    for (int r = 0; r < 4; ++r) {
      const f32x4 mv = *(const f32x4*)&redm[(i * 16 + quad * 4 + r) * 4];
      const float m = fmaxf(fmaxf(mv[0], mv[1]), fmaxf(mv[2], mv[3]));
      float s = 0.f;
#pragma unroll
      for (int j = 0; j < 4; ++j) {
        const float p = __expf(acc[i][j][r] - m);
        acc[i][j][r] = p;
        s += p;
      }
      rsum[i][r] = s;
    }
  }
#pragma unroll
  for (int off = 1; off < 16; off <<= 1)
#pragma unroll
    for (int i = 0; i < 4; ++i)
#pragma unroll
      for (int r = 0; r < 4; ++r) rsum[i][r] += __shfl_xor(rsum[i][r], off, 64);
  if (nl == 0) {
#pragma unroll
    for (int i = 0; i < 4; ++i)
#pragma unroll
      for (int r = 0; r < 4; ++r)
        reds[(i * 16 + quad * 4 + r) * 4 + wn] = rsum[i][r];
  }
  asm volatile("s_waitcnt lgkmcnt(0)" ::: "memory");
  __builtin_amdgcn_s_barrier();
  asm volatile("" ::: "memory");
  // precompute 1/sum BEFORE Ps overwrites reds (aliased) — then barrier
  float invv[4][4];
#pragma unroll
  for (int i = 0; i < 4; ++i)
#pragma unroll
    for (int r = 0; r < 4; ++r) {
      const f32x4 sv = *(const f32x4*)&reds[(i * 16 + quad * 4 + r) * 4];
      invv[i][r] = 1.0f / (sv[0] + sv[1] + sv[2] + sv[3]);
    }
  asm volatile("s_waitcnt lgkmcnt(0)" ::: "memory");
  __builtin_amdgcn_s_barrier();
  asm volatile("" ::: "memory");
  // normalize, write P -> LDS (swizzled row-major 64x256 bf16)
#pragma unroll
  for (int i = 0; i < 4; ++i) {
#pragma unroll
    for (int r = 0; r < 4; ++r) {
      const int row = i * 16 + quad * 4 + r;
#pragma unroll
      for (int j = 0; j < 4; ++j) {
        const int col = wn * 64 + j * 16 + nl;
        float pv = acc[i][j][r] * invv[i][r];
        if (w == 0 && col < 128) pv = 0.0f;  // zero V bucket
        const int cb = col >> 3;
        Ps[row * 256 + (((cb ^ (row & 7)) << 3) | (col & 7))] = f2bf(pv);
      }
    }
  }
  asm volatile("s_waitcnt lgkmcnt(0)" ::: "memory");
  __builtin_amdgcn_s_barrier();
  asm volatile("" ::: "memory");
  // -------- Ps published; NO barriers from here on: waves free-run --------

  // ---- phase 2: out = P @ KWT^T, per-wave 3-deep barrier-free pipeline ----
  f32x4 acc2[4][2];
#pragma unroll
  for (int t2 = 0; t2 < 16; ++t2) {
    const int och = t2 >> 2, kch = t2 & 3;
    unsigned short* const bb = B2BUF(t2 % 3);
    if (kch == 0) {
#pragma unroll
      for (int i = 0; i < 4; ++i)
#pragma unroll
        for (int j = 0; j < 2; ++j) acc2[i][j] = zero;
    }
    // hand-counted per-wave waits (loads 4/chunk; out-stores 32/och-group
    // sit in the in-order queue between load groups — see queue derivation)
    if (t2 == 15)      asm volatile("s_waitcnt vmcnt(0)" ::: "memory");
    else if (t2 == 14) asm volatile("s_waitcnt vmcnt(4)" ::: "memory");
    else if (t2 == 4 || t2 == 5 || t2 == 8 || t2 == 9 || t2 == 12 || t2 == 13)
                       asm volatile("s_waitcnt vmcnt(40)" ::: "memory");
    else               asm volatile("s_waitcnt vmcnt(8)" ::: "memory");
#pragma unroll
    for (int ks = 0; ks < 2; ++ks) {
      const int kb2 = kch * 8 + ks * 4 + quad;
      s16x8 af[4], bf[2];
#pragma unroll
      for (int i = 0; i < 4; ++i)
        af[i] = *(const s16x8*)&Ps[(i * 16 + nl) * 256 + ((kb2 ^ (nl & 7)) << 3)];
#pragma unroll
      for (int j = 0; j < 2; ++j)
        bf[j] = *(const s16x8*)&bb[(wn * 32 + j * 16 + nl) * 64 +
                                   (((ks * 4 + quad) ^ (nl & 7)) * 8)];
      __builtin_amdgcn_s_setprio(1);
#pragma unroll
      for (int i = 0; i < 4; ++i) {
        acc2[i][0] = MFMA_BF16(af[i], bf[0], acc2[i][0]);
        acc2[i][1] = MFMA_BF16(af[i], bf[1], acc2[i][1]);
      }
      __builtin_amdgcn_s_setprio(0);
    }
    if (kch == 3) {  // stores BEFORE next issue (keeps them older in queue)
#pragma unroll
      for (int i = 0; i < 4; ++i) {
        const int seq = w * 128 + half * 64 + i * 16 + quad * 4;
        float* dst = out + (size_t)(b * 8192 + seq) * 512;
#pragma unroll
        for (int j = 0; j < 2; ++j) {
          const int o = och * 128 + wn * 32 + j * 16 + nl;
#pragma unroll
          for (int r = 0; r < 4; ++r) dst[(size_t)r * 512 + o] = acc2[i][j][r] + bo[och][j];
        }
      }
    }
    if (t2 <= 12) {
      // refill the buffer just consumed: this wave's ds_reads of it are
      // retired (lgkm drained before the MFMAs above); own slice only.
      asm volatile("s_waitcnt lgkmcnt(0)" ::: "memory");
      STAGE_B2(t2 + 3, B2BUF((t2 + 3) % 3));
    }
  }
#undef STAGE_P1
#undef STAGE_B2
#undef B2BUF
}

extern "C" void kernel_launch(void* const* d_in, const int* in_sizes, int n_in,
                              void* d_out, int out_size, void* d_ws, size_t ws_size,
                              hipStream_t stream) {
  const float* x = (const float*)d_in[0];
  const float* w_qkv = (const float*)d_in[1];
  const float* w_out = (const float*)d_in[2];
  const float* b_out = (const float*)d_in[3];
  float* out = (float*)d_out;

  char* ws = (char*)d_ws;
  // Layout (97.5 MB, within the 112 MB proven budget):
  //   Q   @  0  (32MB)
  //   K   @ 32M (32MB)
  //   xb  @ 64M (32MB)  dead after gemm_qk
  //   KWT @ 64M (32MB)  written by gemm_kwt (aliases xb)
  //   wb  @ 96M (1MB), wob @ 97M (0.5MB)
  unsigned short* Q = (unsigned short*)ws;
  unsigned short* K = (unsigned short*)(ws + (size_t)33554432);
  unsigned short* xb = (unsigned short*)(ws + (size_t)67108864);
  unsigned short* KWT = (unsigned short*)(ws + (size_t)67108864);
  unsigned short* wb = (unsigned short*)(ws + (size_t)100663296);
  unsigned short* wob = (unsigned short*)(ws + (size_t)100663296 + 1048576);

  cvt_bf16<<<dim3(8576), dim3(256), 0, stream>>>(x, w_qkv, w_out, xb, wb, wob);
  gemm_qk<<<dim3(2048), dim3(256), 0, stream>>>(xb, wb, Q, K);
  gemm_kwt<<<dim3(1024), dim3(256), 0, stream>>>(K, wob, KWT);
  attn64<<<dim3(512), dim3(256), 0, stream>>>(Q, K, KWT, b_out, out);
}